// Round 16
// baseline (1456.930 us; speedup 1.0000x reference)
//
#include <hip/hip_runtime.h>
#include <hip/hip_bf16.h>
#include <cstdint>
#include <cstddef>

// R26: R25 banked (1459->1453us). conv_stats/conv_small bodies FROZEN.
// Change 1 (main): L4 OCG 4->8 (launch param only). H=16 -> each image is
// one tile, so OCGN oc-groups re-stage the SAME 18x18x64 halo; OCG=8 halves
// that redundancy (grid 4608->2304, 9 blocks/CU exact, no tail). Unlike
// R20's L2 regression, L4 is block-count-limited not VGPR-limited
// (64-thread blocks, acc[4][8]=32 regs). Stats per-(n,oc) partials are the
// identical doubles (same 64-lane shuffle); only fp64-atomic order changes
// (R18/R25 precedent, absmax stayed 0).
// Change 2 (micro): stats/nsum/ncnt allocated contiguously -> 1 memset.
// Failure criterion: total >= 1453 -> revert L4 to OCG=4, declare plateau.
// Provenance: R15 PREBN, R18 XCD swizzle, R19 1-barrier dbuf, R23 single-
// pass L5/L6 (max/BN commute, s>0), R24 fused bn_finalize, R25 oc-split.

// ---------------------------------------------------------------------------
// conv_stats: stats pass + pooled-max store. Swizzled 1-D launch (R18).
// PREBN: prologue computes prev-layer scale/shift from raw stats (fused
// bn_finalize), then staging applies relu(fmaf(x,s,t)) -- halo zeros stay 0.
// Block: (TS/2)^2 threads; each thread owns one 2x2 conv quad x OCG ocs.
// Launch: grid.x = 288 * (H/TS)^2 * (OC/OCG), 1-D.  [FROZEN since R19/R24]
// ---------------------------------------------------------------------------
template<int IC, int OC, int H, int TS, int OCG, bool PREBN>
__global__ __launch_bounds__(TS*TS/4)
void conv_stats(const float* __restrict__ inA, const float* __restrict__ inB,
                int nSplit, const float* __restrict__ W,
                const double* __restrict__ pstats, const float* __restrict__ pgam,
                const float* __restrict__ pbet, double pcnt0, double pcnt1,
                double* __restrict__ stats, float* __restrict__ maxout,
                int nSupport)
{
  constexpr int TH = TS/2;
  constexpr int NT = TH*TH;
  constexpr int NW = (NT+63)/64;
  constexpr int TILES = H/TS;
  constexpr int SH = TILES*TILES;     // tiles per image
  constexpr int OCGN = OC/OCG;        // oc-groups (halo sharers)
  constexpr int SZ = (TS+2)*(TS+2);

  const int tid = threadIdx.x;

  // ---- XCD-aware decode: sharers (same slot, varying o) are == mod 8 ----
  const int w     = blockIdx.x % (8*OCGN);
  const int chunk = blockIdx.x / (8*OCGN);
  const int ocg   = w >> 3;           // o
  const int slot  = chunk*8 + (w & 7);
  const int n     = slot / SH;
  const int t     = slot % SH;
  const int ty0 = (t / TILES) * TS;
  const int tx0 = (t % TILES) * TS;

  const float* in = (n < nSplit) ? inA + (size_t)n*IC*H*H
                                 : inB + (size_t)(n - nSplit)*IC*H*H;
  const float* Wb = W + (size_t)(ocg*OCG)*IC*9;   // uniform per block
  const int g = (n < nSupport) ? 0 : 1;

  __shared__ float sIn[2][SZ];
  __shared__ float sSum[NW][OCG], sSsq[NW][OCG];
  __shared__ float sScl[PREBN ? IC : 1], sShf[PREBN ? IC : 1];

  // fused bn_finalize of the PREVIOUS layer (bit-identical arithmetic)
  if constexpr (PREBN) {
    for (int i = tid; i < IC; i += NT) {
      double cnt  = (g == 0) ? pcnt0 : pcnt1;
      double mean = pstats[((size_t)g*IC + i)*2 + 0] / cnt;
      double var  = pstats[((size_t)g*IC + i)*2 + 1] / cnt - mean*mean;
      double inv  = 1.0 / sqrt(var + 1e-5);
      double ga = (double)pgam[i];
      double be = (double)pbet[i];
      sScl[i] = (float)(ga * inv);
      sShf[i] = (float)(be - mean * ga * inv);
    }
    __syncthreads();
  }

  float acc[4][OCG];
  #pragma unroll
  for (int i = 0; i < 4; ++i)
    #pragma unroll
    for (int o = 0; o < OCG; ++o) acc[i][o] = 0.f;

  const int tx = tid % TH, ty = tid / TH;
  const int iy = 2*ty, ix = 2*tx;

  for (int ic = 0; ic < IC; ++ic) {
    float* sBuf = sIn[ic & 1];
    const float* ip = in + (size_t)ic*H*H;
    float ps = 0.f, pt = 0.f;
    if constexpr (PREBN) { ps = sScl[ic]; pt = sShf[ic]; }
    for (int i = tid; i < SZ; i += NT) {
      int r = i/(TS+2), c = i%(TS+2);
      int gy = ty0 + r - 1, gx = tx0 + c - 1;
      float v = 0.f;
      if (gy >= 0 && gy < H && gx >= 0 && gx < H) {
        v = ip[gy*H + gx];
        if constexpr (PREBN)   // halo must stay 0, not relu(t)
          v = fmaxf(fmaf(v, ps, pt), 0.f);
      }
      sBuf[i] = v;
    }
    __syncthreads();

    float xr[4][4];
    #pragma unroll
    for (int r = 0; r < 4; ++r)
      #pragma unroll
      for (int c = 0; c < 4; ++c)
        xr[r][c] = sBuf[(iy+r)*(TS+2) + ix + c];

    #pragma unroll
    for (int oc = 0; oc < OCG; ++oc) {
      const float* wp = Wb + (size_t)oc*IC*9 + ic*9;   // uniform -> s_load
      float w9[9];
      #pragma unroll
      for (int k = 0; k < 9; ++k) w9[k] = wp[k];
      #pragma unroll
      for (int kh = 0; kh < 3; ++kh) {
        #pragma unroll
        for (int kw = 0; kw < 3; ++kw) {
          const float wv = w9[kh*3 + kw];
          acc[0][oc] = fmaf(xr[kh  ][kw  ], wv, acc[0][oc]);
          acc[1][oc] = fmaf(xr[kh  ][kw+1], wv, acc[1][oc]);
          acc[2][oc] = fmaf(xr[kh+1][kw  ], wv, acc[2][oc]);
          acc[3][oc] = fmaf(xr[kh+1][kw+1], wv, acc[3][oc]);
        }
      }
    }
    // no trailing barrier: next iteration stages the OTHER buffer; a wave
    // can only reach stage(ic+2) (same buffer) after all waves passed
    // barrier(ic+1), i.e. after every compute(ic) completed.
  }

  // pooled-max store (raw conv; next layer applies this layer's BN on load)
  {
    const int py = ty0/2 + ty, px = tx0/2 + tx;
    #pragma unroll
    for (int oc = 0; oc < OCG; ++oc) {
      const int ocGl = ocg*OCG + oc;
      float mx = fmaxf(fmaxf(acc[0][oc], acc[1][oc]),
                       fmaxf(acc[2][oc], acc[3][oc]));
      maxout[(((size_t)n*OC + ocGl)*(H/2) + py)*(H/2) + px] = mx;
    }
  }

  // stats reduction (unchanged arithmetic/order -> bit-identical stats)
  const int lane = tid & 63, wid = tid >> 6;
  #pragma unroll
  for (int oc = 0; oc < OCG; ++oc) {
    float ls = acc[0][oc] + acc[1][oc] + acc[2][oc] + acc[3][oc];
    float lq = acc[0][oc]*acc[0][oc] + acc[1][oc]*acc[1][oc]
             + acc[2][oc]*acc[2][oc] + acc[3][oc]*acc[3][oc];
    #pragma unroll
    for (int off = 32; off > 0; off >>= 1) {
      ls += __shfl_down(ls, off);
      lq += __shfl_down(lq, off);
    }
    if (lane == 0) { sSum[wid][oc] = ls; sSsq[wid][oc] = lq; }
  }
  __syncthreads();
  if (tid < OCG) {
    float S = 0.f, Q = 0.f;
    #pragma unroll
    for (int w2 = 0; w2 < NW; ++w2) { S += sSum[w2][tid]; Q += sSsq[w2][tid]; }
    const int ocGl = ocg*OCG + tid;
    atomicAdd(&stats[(g*OC + ocGl)*2 + 0], (double)S);
    atomicAdd(&stats[(g*OC + ocGl)*2 + 1], (double)Q);
  }
}

// ---------------------------------------------------------------------------
// Tiny layers (L5 H=8, L6 H=4), 2-way oc-split: grid 576, 128 threads.
// bid = n*2 + half; oc = (tid&31) + 32*half; q = tid>>5. Single pass =
// fused prev-layer bn_finalize + PREBN staging + conv + stats + raw
// pooled-max (R23 identity). Consumers apply this layer's BN on load.
// ---------------------------------------------------------------------------
template<int H>
__global__ __launch_bounds__(128)
void conv_small(const float* __restrict__ in, const float* __restrict__ W,
                const double* __restrict__ pstats, const float* __restrict__ pgam,
                const float* __restrict__ pbet, double pcnt0, double pcnt1,
                double* __restrict__ stats, float* __restrict__ out, int nSupport)
{
  constexpr int HW = H*H;
  constexpr int NACC = (H == 8) ? 16 : 4;
  constexpr int SC = (H == 4) ? 32*16 : 1;
  const int tid  = threadIdx.x;          // [0,128)
  const int n    = blockIdx.x >> 1;
  const int half = blockIdx.x & 1;
  const int ocL  = tid & 31;             // oc within this half
  const int oc   = ocL + 32*half;        // global oc (weights/output)
  const int q    = tid >> 5;             // [0,4)
  const int g = (n < nSupport) ? 0 : 1;

  __shared__ float sX[64*HW];
  __shared__ float sS[128];
  __shared__ float sQ[128];
  __shared__ float sC[SC];
  __shared__ float sScl[64], sShf[64];

  // fused bn_finalize of the PREVIOUS layer (bit-identical arithmetic)
  if (tid < 64) {
    double cnt  = (g == 0) ? pcnt0 : pcnt1;
    double mean = pstats[((size_t)g*64 + tid)*2 + 0] / cnt;
    double var  = pstats[((size_t)g*64 + tid)*2 + 1] / cnt - mean*mean;
    double inv  = 1.0 / sqrt(var + 1e-5);
    double ga = (double)pgam[tid];
    double be = (double)pbet[tid];
    sScl[tid] = (float)(ga * inv);
    sShf[tid] = (float)(be - mean * ga * inv);
  }
  __syncthreads();

  for (int i = tid; i < 64*HW; i += 128) {
    int ic = i / HW;   // HW is a power of 2
    sX[i] = fmaxf(fmaf(in[(size_t)n*64*HW + i], sScl[ic], sShf[ic]), 0.f);
  }
  __syncthreads();

  float acc[NACC];
  #pragma unroll
  for (int i = 0; i < NACC; ++i) acc[i] = 0.f;

  const int ry = (H == 8) ? 4*(q >> 1) : 0;
  const int rx = (H == 8) ? 4*(q & 1)  : 0;

  for (int ic = 0; ic < 64; ++ic) {
    const float* wp = W + ((size_t)oc*64 + ic)*9;
    float w[9];
    #pragma unroll
    for (int k = 0; k < 9; ++k) w[k] = wp[k];
    if (H == 8) {
      float rin[6][6];
      #pragma unroll
      for (int r = 0; r < 6; ++r) {
        int y = ry + r - 1;
        #pragma unroll
        for (int c = 0; c < 6; ++c) {
          int x = rx + c - 1;
          rin[r][c] = (y >= 0 && y < H && x >= 0 && x < H) ? sX[ic*HW + y*H + x] : 0.f;
        }
      }
      #pragma unroll
      for (int kh = 0; kh < 3; ++kh)
        #pragma unroll
        for (int kw = 0; kw < 3; ++kw) {
          float wv = w[kh*3+kw];
          #pragma unroll
          for (int py = 0; py < 4; ++py)
            #pragma unroll
            for (int px = 0; px < 4; ++px)
              acc[py*4+px] = fmaf(wv, rin[py+kh][px+kw], acc[py*4+px]);
        }
    } else {
      float rin[3][6];
      #pragma unroll
      for (int r = 0; r < 3; ++r) {
        int y = q + r - 1;
        #pragma unroll
        for (int c = 0; c < 6; ++c) {
          int x = c - 1;
          rin[r][c] = (y >= 0 && y < H && x >= 0 && x < H) ? sX[ic*HW + y*H + x] : 0.f;
        }
      }
      #pragma unroll
      for (int kh = 0; kh < 3; ++kh)
        #pragma unroll
        for (int kw = 0; kw < 3; ++kw) {
          float wv = w[kh*3+kw];
          #pragma unroll
          for (int px = 0; px < 4; ++px)
            acc[px] = fmaf(wv, rin[kh][px+kw], acc[px]);
        }
    }
  }

  // stats: same per-(oc,q) float partials as before; per-oc S/Q are the same
  // 4 floats summed in the same q-order -> identical doubles into atomics.
  {
    float ls = 0.f, lq = 0.f;
    #pragma unroll
    for (int i = 0; i < NACC; ++i) { ls += acc[i]; lq += acc[i]*acc[i]; }
    sS[tid] = ls; sQ[tid] = lq;
    __syncthreads();
    if (tid < 32) {
      float S = sS[tid] + sS[tid+32] + sS[tid+64] + sS[tid+96];
      float Q = sQ[tid] + sQ[tid+32] + sQ[tid+64] + sQ[tid+96];
      const int ocGl = tid + 32*half;
      atomicAdd(&stats[(g*64 + ocGl)*2 + 0], (double)S);
      atomicAdd(&stats[(g*64 + ocGl)*2 + 1], (double)Q);
    }
  }
  // raw pooled-max store
  if (H == 8) {
    const int py0 = ry/2, px0 = rx/2;
    #pragma unroll
    for (int pj = 0; pj < 2; ++pj)
      #pragma unroll
      for (int pi = 0; pi < 2; ++pi) {
        float mx = fmaxf(
            fmaxf(acc[(2*pj  )*4 + 2*pi], acc[(2*pj  )*4 + 2*pi+1]),
            fmaxf(acc[(2*pj+1)*4 + 2*pi], acc[(2*pj+1)*4 + 2*pi+1]));
        out[(((size_t)n*64 + oc)*4 + (py0+pj))*4 + (px0+pi)] = mx;
      }
  } else {
    __syncthreads();
    #pragma unroll
    for (int px = 0; px < 4; ++px)
      sC[ocL*16 + q*4 + px] = acc[px];
    __syncthreads();
    int oc2 = tid & 31, pj = (tid >> 5) & 1, pi = (tid >> 6) & 1;
    float m = fmaxf(
        fmaxf(sC[oc2*16 + (2*pj  )*4 + 2*pi], sC[oc2*16 + (2*pj  )*4 + 2*pi+1]),
        fmaxf(sC[oc2*16 + (2*pj+1)*4 + 2*pi], sC[oc2*16 + (2*pj+1)*4 + 2*pi+1]));
    out[(((size_t)n*64 + (oc2 + 32*half))*2 + pj)*2 + pi] = m;
  }
}

// ---------------------------------------------------------------------------
// Head: graph_means / edge_cos consume the RAW L6 pooled-max and apply L6's
// BN on load (fused bn_finalize in prologue; bit-identical arithmetic).
// feat layout [n,64,2,2] -> dim d: oc = d>>2.
// ---------------------------------------------------------------------------
__global__ void graph_means(const float* __restrict__ raw,
                            const double* __restrict__ st,
                            const float* __restrict__ gam, const float* __restrict__ bet,
                            float* __restrict__ s_cat, float* __restrict__ p_cat)
{
  int gb = blockIdx.x, d = threadIdx.x;
  const int gg = (gb < 48) ? 0 : 1;      // block's nodes are all one group
  __shared__ float sScl[64], sShf[64];
  if (d < 64) {
    double cnt  = (gg == 0) ? 192.0*4*4 : 96.0*4*4;   // L6 spatial = 4x4
    double mean = st[((size_t)gg*64 + d)*2 + 0] / cnt;
    double var  = st[((size_t)gg*64 + d)*2 + 1] / cnt - mean*mean;
    double inv  = 1.0 / sqrt(var + 1e-5);
    double ga = (double)gam[d];
    double be = (double)bet[d];
    sScl[d] = (float)(ga * inv);
    sShf[d] = (float)(be - mean * ga * inv);
  }
  __syncthreads();
  const float s = sScl[d >> 2], t = sShf[d >> 2];
  if (gb < 48) {
    float v = 0.f;
    for (int i = 0; i < 4; ++i)
      v += fmaxf(fmaf(raw[(size_t)(4*gb + i)*256 + d], s, t), 0.f);
    s_cat[gb*256 + d] = v * 0.25f;
  } else {
    int qg = gb - 48;
    float v = 0.f;
    for (int i = 0; i < 4; ++i)
      v += fmaxf(fmaf(raw[(size_t)(192 + 4*qg + i)*256 + d], s, t), 0.f);
    p_cat[qg*256 + d] = v * 0.25f;
  }
}

__global__ void edge_cos(const float* __restrict__ raw,
                         const double* __restrict__ st,
                         const float* __restrict__ gam, const float* __restrict__ bet,
                         const int* __restrict__ ei,
                         float* __restrict__ nsum, float* __restrict__ ncnt, int nEdges)
{
  int e = blockIdx.x, lane = threadIdx.x;
  __shared__ float sScl[64], sShf[64];
  {   // support edges only -> g = 0
    double cnt  = 192.0*4*4;
    double mean = st[(size_t)lane*2 + 0] / cnt;
    double var  = st[(size_t)lane*2 + 1] / cnt - mean*mean;
    double inv  = 1.0 / sqrt(var + 1e-5);
    double ga = (double)gam[lane];
    double be = (double)bet[lane];
    sScl[lane] = (float)(ga * inv);
    sShf[lane] = (float)(be - mean * ga * inv);
  }
  __syncthreads();
  int src = ei[e], dst = ei[nEdges + e];
  float dot = 0.f, nj = 0.f, ni = 0.f;
  for (int j = lane; j < 256; j += 64) {
    float s = sScl[j >> 2], t = sShf[j >> 2];
    float a = fmaxf(fmaf(raw[(size_t)src*256 + j], s, t), 0.f);
    float b = fmaxf(fmaf(raw[(size_t)dst*256 + j], s, t), 0.f);
    dot += a*b; nj += a*a; ni += b*b;
  }
  for (int off = 32; off > 0; off >>= 1) {
    dot += __shfl_down(dot, off);
    nj  += __shfl_down(nj,  off);
    ni  += __shfl_down(ni,  off);
  }
  if (lane == 0) {
    float denom = fmaxf(sqrtf(nj)*sqrtf(ni), 1e-6f);
    atomicAdd(&nsum[dst], dot/denom);
    atomicAdd(&ncnt[dst], 1.f);
  }
}

__global__ void cos_loss_k(const float* __restrict__ nsum, const float* __restrict__ ncnt,
                           float* __restrict__ cosloss)
{
  int g = threadIdx.x;
  float v = 0.f;
  if (g < 48) {
    float gm = 0.f;
    for (int i = 0; i < 4; ++i) {
      int nd = 4*g + i;
      gm += nsum[nd] / fmaxf(ncnt[nd], 1.f);
    }
    gm *= 0.25f;
    v = (gm - 1.f)*(gm - 1.f);
  }
  for (int off = 32; off > 0; off >>= 1) v += __shfl_down(v, off);
  if (g == 0) cosloss[0] = v;
}

__global__ void pd_out(const float* __restrict__ s_cat, const float* __restrict__ p_cat,
                       const int* __restrict__ support_y, const int* __restrict__ query_y,
                       float* __restrict__ ce, float* __restrict__ correct)
{
  const int q = blockIdx.x;
  const int tid = threadIdx.x, lane = tid & 63, wid = tid >> 6;
  __shared__ float sP[48];
  __shared__ float sOut[24];
  float pv[4];
  #pragma unroll
  for (int j = 0; j < 4; ++j) pv[j] = p_cat[(size_t)q*256 + lane + 64*j];
  for (int s = wid*12; s < wid*12 + 12; ++s) {
    float d2 = 0.f;
    #pragma unroll
    for (int j = 0; j < 4; ++j) {
      float diff = pv[j] - s_cat[(size_t)s*256 + lane + 64*j];
      d2 += diff*diff;
    }
    for (int off = 32; off > 0; off >>= 1) d2 += __shfl_down(d2, off);
    if (lane == 0) sP[s] = expf(-d2);
  }
  __syncthreads();
  if (tid < 24) {
    int c = tid; float sum = 0.f; int cnt = 0;
    for (int s = 0; s < 48; ++s)
      if (support_y[s] == c) { sum += sP[s]; ++cnt; }
    sOut[c] = sum / fmaxf((float)cnt, 1.f);
  }
  __syncthreads();
  if (tid == 0) {
    float m = sOut[0]; int am = 0;
    for (int c = 1; c < 24; ++c) if (sOut[c] > m) { m = sOut[c]; am = c; }
    float lse = 0.f;
    for (int c = 0; c < 24; ++c) lse += expf(sOut[c] - m);
    lse = m + logf(lse);
    int y = query_y[q];
    ce[q] = lse - sOut[y];
    correct[q] = (am == y) ? 1.f : 0.f;
  }
}

__global__ void final_k(const float* __restrict__ ce, const float* __restrict__ correct,
                        const float* __restrict__ cosloss, float* __restrict__ out)
{
  if (threadIdx.x == 0) {
    float s = 0.f, a = 0.f;
    for (int qq = 0; qq < 24; ++qq) { s += ce[qq]; a += correct[qq]; }
    float atten = ce[5];
    float rest  = (s - atten) / 23.f;
    float cl = cosloss[0];
    out[0] = atten + rest + cl;
    out[1] = a;
    out[2] = cl;
    out[3] = atten;
    out[4] = rest;
  }
}

// ---------------------------------------------------------------------------
extern "C" void kernel_launch(void* const* d_in, const int* in_sizes, int n_in,
                              void* d_out, int out_size, void* d_ws, size_t ws_size,
                              hipStream_t stream)
{
  const float* support_x = (const float*)d_in[0];
  const float* query_x   = (const float*)d_in[1];
  const int*   s_ei      = (const int*)d_in[2];
  const int*   s_y       = (const int*)d_in[6];
  const int*   q_y       = (const int*)d_in[7];
  const float* w1 = (const float*)d_in[8];
  const float* g1 = (const float*)d_in[9];
  const float* b1 = (const float*)d_in[10];
  const float* w2 = (const float*)d_in[11];
  const float* g2 = (const float*)d_in[12];
  const float* b2 = (const float*)d_in[13];
  const float* wr = (const float*)d_in[14];
  const float* gr = (const float*)d_in[15];
  const float* br = (const float*)d_in[16];
  (void)in_sizes; (void)n_in; (void)out_size;

  char* ws = (char*)d_ws;
  size_t off = 0;
  auto alloc = [&](size_t bytes) -> char* {
    char* p = ws + off;
    off = (off + bytes + 255) & ~(size_t)255;
    return p;
  };
  float*  actA  = (float*)alloc((size_t)288*32*64*64*4);   // 151 MB (L1 max-plane)
  float*  actB  = (float*)alloc((size_t)288*64*32*32*4);   // 75.5 MB (L2 max-plane)
  double* stats = (double*)alloc(6*256*8);                 // 12288 B (6 layer slots)
  float*  nsum  = (float*)alloc(192*4);                    // 768 B (contiguous w/ stats)
  float*  ncnt  = (float*)alloc(192*4);                    // 768 B
  float*  s_cat = (float*)alloc(48*256*4);
  float*  p_cat = (float*)alloc(24*256*4);
  float*  cosl  = (float*)alloc(256);
  float*  ce    = (float*)alloc(24*4);
  float*  corr  = (float*)alloc(24*4);
  if (off > ws_size) return;   // ~227 MB, known to fit

  const int NS = 192;
  const int BIG = 1 << 30;

  // L3-L6 planes reuse actA space (dead after L2 stats consumed it)
  float* mx3   = actA;                                    // 18.9 MB
  float* mx4   = actA + (size_t)288*64*16*16;             // 4.7 MB
  float* rawm5 = mx4  + (size_t)288*64*8*8;               // 1.2 MB (L5 raw pooled-max)
  float* rawm6 = rawm5 + (size_t)288*64*4*4;              // 0.3 MB (L6 raw pooled-max)

  // single memset covers stats (12288B, 256-mult) + nsum (768) + ncnt (768)
  hipMemsetAsync(stats, 0, 6*256*8 + 192*4 + 192*4, stream);

  // ---- L1: 3->32 @128, raw input. grid 288*16*2 = 9216
  conv_stats<3,32,128,32,16,false><<<9216,256,0,stream>>>(
      support_x, query_x, 192, w1, nullptr, nullptr, nullptr, 0.0, 0.0,
      stats, actA, NS);

  // ---- L2: 32->64 @64, PREBN(L1 via fused finalize). grid 4608
  conv_stats<32,64,64,32,16,true><<<4608,256,0,stream>>>(
      actA, actA, BIG, w2, stats, g1, b1, 192.0*128*128, 96.0*128*128,
      stats+256, actB, NS);

  // ---- L3: 64->64 @32, PREBN(L2). grid 1152
  conv_stats<64,64,32,32,16,true><<<1152,256,0,stream>>>(
      actB, actB, BIG, wr + 0*36864, stats+256, g2, b2, 192.0*64*64, 96.0*64*64,
      stats+512, mx3, NS);

  // ---- L4: 64->64 @16, PREBN(L3). OCG=8: grid 2304 (halved halo re-staging)
  conv_stats<64,64,16,16,8,true><<<2304,64,0,stream>>>(
      mx3, mx3, BIG, wr + 1*36864, stats+512, gr + 0*64, br + 0*64,
      192.0*32*32, 96.0*32*32, stats+768, mx4, NS);

  // ---- L5: 64->64 @8, PREBN(L4) -> stats + raw pooled-max. 2-way oc-split.
  conv_small<8><<<576,128,0,stream>>>(
      mx4, wr + 2*36864, stats+768, gr + 1*64, br + 1*64,
      192.0*16*16, 96.0*16*16, stats+1024, rawm5, NS);

  // ---- L6: 64->64 @4, PREBN(L5) consuming rawm5 directly. 2-way oc-split.
  conv_small<4><<<576,128,0,stream>>>(
      rawm5, wr + 3*36864, stats+1024, gr + 2*64, br + 2*64,
      192.0*8*8, 96.0*8*8, stats+1280, rawm6, NS);

  // ---- head: L6 BN applied on load from rawm6
  graph_means<<<72,256,0,stream>>>(rawm6, stats+1280, gr + 3*64, br + 3*64,
                                   s_cat, p_cat);
  edge_cos<<<768,64,0,stream>>>(rawm6, stats+1280, gr + 3*64, br + 3*64,
                                s_ei, nsum, ncnt, 768);
  cos_loss_k<<<1,64,0,stream>>>(nsum, ncnt, cosl);
  pd_out<<<24,256,0,stream>>>(s_cat, p_cat, s_y, q_y, ce, corr);
  final_k<<<1,64,0,stream>>>(ce, corr, cosl, (float*)d_out);
}

// Round 17
// 1438.771 us; speedup vs baseline: 1.0126x; 1.0126x over previous
//
#include <hip/hip_runtime.h>
#include <hip/hip_bf16.h>
#include <cstdint>
#include <cstddef>

// R27: R26 (L4 OCG=8) hit its failure criterion (1457 >= 1453) -- the halved
// halo re-staging was cancelled by the occupancy drop (4.5->2.25 waves/SIMD
// on 64-thread blocks). Per pre-commit: REVERT L4 to OCG=4. Keep the
// single-memset micro. This is the R25 configuration (best verified:
// 1453us), re-banked. Conv bodies FROZEN -- plateau established across six
// structural attempts (R14/R16/R17/R20/R21/R26): every knob trades VALU
// issue vs idle ~1:1 at this occupancy; the 2-phase loop is the compiler's
// local optimum. Not a HW roofline (L2 conv: 44% of FMA-issue floor,
// VALUBusy 72%, HBM 5%) but the practical ceiling of this formulation.
// Provenance: R15 PREBN, R18 XCD swizzle (FETCH 305->153MB), R19 1-barrier
// dbuf, R23 single-pass L5/L6 (max/BN commute, s>0), R24 fused bn_finalize,
// R25 2-way oc-split tiny layers.

// ---------------------------------------------------------------------------
// conv_stats: stats pass + pooled-max store. Swizzled 1-D launch (R18).
// PREBN: prologue computes prev-layer scale/shift from raw stats (fused
// bn_finalize), then staging applies relu(fmaf(x,s,t)) -- halo zeros stay 0.
// Block: (TS/2)^2 threads; each thread owns one 2x2 conv quad x OCG ocs.
// Launch: grid.x = 288 * (H/TS)^2 * (OC/OCG), 1-D.  [FROZEN since R19/R24]
// ---------------------------------------------------------------------------
template<int IC, int OC, int H, int TS, int OCG, bool PREBN>
__global__ __launch_bounds__(TS*TS/4)
void conv_stats(const float* __restrict__ inA, const float* __restrict__ inB,
                int nSplit, const float* __restrict__ W,
                const double* __restrict__ pstats, const float* __restrict__ pgam,
                const float* __restrict__ pbet, double pcnt0, double pcnt1,
                double* __restrict__ stats, float* __restrict__ maxout,
                int nSupport)
{
  constexpr int TH = TS/2;
  constexpr int NT = TH*TH;
  constexpr int NW = (NT+63)/64;
  constexpr int TILES = H/TS;
  constexpr int SH = TILES*TILES;     // tiles per image
  constexpr int OCGN = OC/OCG;        // oc-groups (halo sharers)
  constexpr int SZ = (TS+2)*(TS+2);

  const int tid = threadIdx.x;

  // ---- XCD-aware decode: sharers (same slot, varying o) are == mod 8 ----
  const int w     = blockIdx.x % (8*OCGN);
  const int chunk = blockIdx.x / (8*OCGN);
  const int ocg   = w >> 3;           // o
  const int slot  = chunk*8 + (w & 7);
  const int n     = slot / SH;
  const int t     = slot % SH;
  const int ty0 = (t / TILES) * TS;
  const int tx0 = (t % TILES) * TS;

  const float* in = (n < nSplit) ? inA + (size_t)n*IC*H*H
                                 : inB + (size_t)(n - nSplit)*IC*H*H;
  const float* Wb = W + (size_t)(ocg*OCG)*IC*9;   // uniform per block
  const int g = (n < nSupport) ? 0 : 1;

  __shared__ float sIn[2][SZ];
  __shared__ float sSum[NW][OCG], sSsq[NW][OCG];
  __shared__ float sScl[PREBN ? IC : 1], sShf[PREBN ? IC : 1];

  // fused bn_finalize of the PREVIOUS layer (bit-identical arithmetic)
  if constexpr (PREBN) {
    for (int i = tid; i < IC; i += NT) {
      double cnt  = (g == 0) ? pcnt0 : pcnt1;
      double mean = pstats[((size_t)g*IC + i)*2 + 0] / cnt;
      double var  = pstats[((size_t)g*IC + i)*2 + 1] / cnt - mean*mean;
      double inv  = 1.0 / sqrt(var + 1e-5);
      double ga = (double)pgam[i];
      double be = (double)pbet[i];
      sScl[i] = (float)(ga * inv);
      sShf[i] = (float)(be - mean * ga * inv);
    }
    __syncthreads();
  }

  float acc[4][OCG];
  #pragma unroll
  for (int i = 0; i < 4; ++i)
    #pragma unroll
    for (int o = 0; o < OCG; ++o) acc[i][o] = 0.f;

  const int tx = tid % TH, ty = tid / TH;
  const int iy = 2*ty, ix = 2*tx;

  for (int ic = 0; ic < IC; ++ic) {
    float* sBuf = sIn[ic & 1];
    const float* ip = in + (size_t)ic*H*H;
    float ps = 0.f, pt = 0.f;
    if constexpr (PREBN) { ps = sScl[ic]; pt = sShf[ic]; }
    for (int i = tid; i < SZ; i += NT) {
      int r = i/(TS+2), c = i%(TS+2);
      int gy = ty0 + r - 1, gx = tx0 + c - 1;
      float v = 0.f;
      if (gy >= 0 && gy < H && gx >= 0 && gx < H) {
        v = ip[gy*H + gx];
        if constexpr (PREBN)   // halo must stay 0, not relu(t)
          v = fmaxf(fmaf(v, ps, pt), 0.f);
      }
      sBuf[i] = v;
    }
    __syncthreads();

    float xr[4][4];
    #pragma unroll
    for (int r = 0; r < 4; ++r)
      #pragma unroll
      for (int c = 0; c < 4; ++c)
        xr[r][c] = sBuf[(iy+r)*(TS+2) + ix + c];

    #pragma unroll
    for (int oc = 0; oc < OCG; ++oc) {
      const float* wp = Wb + (size_t)oc*IC*9 + ic*9;   // uniform -> s_load
      float w9[9];
      #pragma unroll
      for (int k = 0; k < 9; ++k) w9[k] = wp[k];
      #pragma unroll
      for (int kh = 0; kh < 3; ++kh) {
        #pragma unroll
        for (int kw = 0; kw < 3; ++kw) {
          const float wv = w9[kh*3 + kw];
          acc[0][oc] = fmaf(xr[kh  ][kw  ], wv, acc[0][oc]);
          acc[1][oc] = fmaf(xr[kh  ][kw+1], wv, acc[1][oc]);
          acc[2][oc] = fmaf(xr[kh+1][kw  ], wv, acc[2][oc]);
          acc[3][oc] = fmaf(xr[kh+1][kw+1], wv, acc[3][oc]);
        }
      }
    }
    // no trailing barrier: next iteration stages the OTHER buffer; a wave
    // can only reach stage(ic+2) (same buffer) after all waves passed
    // barrier(ic+1), i.e. after every compute(ic) completed.
  }

  // pooled-max store (raw conv; next layer applies this layer's BN on load)
  {
    const int py = ty0/2 + ty, px = tx0/2 + tx;
    #pragma unroll
    for (int oc = 0; oc < OCG; ++oc) {
      const int ocGl = ocg*OCG + oc;
      float mx = fmaxf(fmaxf(acc[0][oc], acc[1][oc]),
                       fmaxf(acc[2][oc], acc[3][oc]));
      maxout[(((size_t)n*OC + ocGl)*(H/2) + py)*(H/2) + px] = mx;
    }
  }

  // stats reduction (unchanged arithmetic/order -> bit-identical stats)
  const int lane = tid & 63, wid = tid >> 6;
  #pragma unroll
  for (int oc = 0; oc < OCG; ++oc) {
    float ls = acc[0][oc] + acc[1][oc] + acc[2][oc] + acc[3][oc];
    float lq = acc[0][oc]*acc[0][oc] + acc[1][oc]*acc[1][oc]
             + acc[2][oc]*acc[2][oc] + acc[3][oc]*acc[3][oc];
    #pragma unroll
    for (int off = 32; off > 0; off >>= 1) {
      ls += __shfl_down(ls, off);
      lq += __shfl_down(lq, off);
    }
    if (lane == 0) { sSum[wid][oc] = ls; sSsq[wid][oc] = lq; }
  }
  __syncthreads();
  if (tid < OCG) {
    float S = 0.f, Q = 0.f;
    #pragma unroll
    for (int w2 = 0; w2 < NW; ++w2) { S += sSum[w2][tid]; Q += sSsq[w2][tid]; }
    const int ocGl = ocg*OCG + tid;
    atomicAdd(&stats[(g*OC + ocGl)*2 + 0], (double)S);
    atomicAdd(&stats[(g*OC + ocGl)*2 + 1], (double)Q);
  }
}

// ---------------------------------------------------------------------------
// Tiny layers (L5 H=8, L6 H=4), 2-way oc-split: grid 576, 128 threads.
// bid = n*2 + half; oc = (tid&31) + 32*half; q = tid>>5. Single pass =
// fused prev-layer bn_finalize + PREBN staging + conv + stats + raw
// pooled-max (R23 identity). Consumers apply this layer's BN on load.
// ---------------------------------------------------------------------------
template<int H>
__global__ __launch_bounds__(128)
void conv_small(const float* __restrict__ in, const float* __restrict__ W,
                const double* __restrict__ pstats, const float* __restrict__ pgam,
                const float* __restrict__ pbet, double pcnt0, double pcnt1,
                double* __restrict__ stats, float* __restrict__ out, int nSupport)
{
  constexpr int HW = H*H;
  constexpr int NACC = (H == 8) ? 16 : 4;
  constexpr int SC = (H == 4) ? 32*16 : 1;
  const int tid  = threadIdx.x;          // [0,128)
  const int n    = blockIdx.x >> 1;
  const int half = blockIdx.x & 1;
  const int ocL  = tid & 31;             // oc within this half
  const int oc   = ocL + 32*half;        // global oc (weights/output)
  const int q    = tid >> 5;             // [0,4)
  const int g = (n < nSupport) ? 0 : 1;

  __shared__ float sX[64*HW];
  __shared__ float sS[128];
  __shared__ float sQ[128];
  __shared__ float sC[SC];
  __shared__ float sScl[64], sShf[64];

  // fused bn_finalize of the PREVIOUS layer (bit-identical arithmetic)
  if (tid < 64) {
    double cnt  = (g == 0) ? pcnt0 : pcnt1;
    double mean = pstats[((size_t)g*64 + tid)*2 + 0] / cnt;
    double var  = pstats[((size_t)g*64 + tid)*2 + 1] / cnt - mean*mean;
    double inv  = 1.0 / sqrt(var + 1e-5);
    double ga = (double)pgam[tid];
    double be = (double)pbet[tid];
    sScl[tid] = (float)(ga * inv);
    sShf[tid] = (float)(be - mean * ga * inv);
  }
  __syncthreads();

  for (int i = tid; i < 64*HW; i += 128) {
    int ic = i / HW;   // HW is a power of 2
    sX[i] = fmaxf(fmaf(in[(size_t)n*64*HW + i], sScl[ic], sShf[ic]), 0.f);
  }
  __syncthreads();

  float acc[NACC];
  #pragma unroll
  for (int i = 0; i < NACC; ++i) acc[i] = 0.f;

  const int ry = (H == 8) ? 4*(q >> 1) : 0;
  const int rx = (H == 8) ? 4*(q & 1)  : 0;

  for (int ic = 0; ic < 64; ++ic) {
    const float* wp = W + ((size_t)oc*64 + ic)*9;
    float w[9];
    #pragma unroll
    for (int k = 0; k < 9; ++k) w[k] = wp[k];
    if (H == 8) {
      float rin[6][6];
      #pragma unroll
      for (int r = 0; r < 6; ++r) {
        int y = ry + r - 1;
        #pragma unroll
        for (int c = 0; c < 6; ++c) {
          int x = rx + c - 1;
          rin[r][c] = (y >= 0 && y < H && x >= 0 && x < H) ? sX[ic*HW + y*H + x] : 0.f;
        }
      }
      #pragma unroll
      for (int kh = 0; kh < 3; ++kh)
        #pragma unroll
        for (int kw = 0; kw < 3; ++kw) {
          float wv = w[kh*3+kw];
          #pragma unroll
          for (int py = 0; py < 4; ++py)
            #pragma unroll
            for (int px = 0; px < 4; ++px)
              acc[py*4+px] = fmaf(wv, rin[py+kh][px+kw], acc[py*4+px]);
        }
    } else {
      float rin[3][6];
      #pragma unroll
      for (int r = 0; r < 3; ++r) {
        int y = q + r - 1;
        #pragma unroll
        for (int c = 0; c < 6; ++c) {
          int x = c - 1;
          rin[r][c] = (y >= 0 && y < H && x >= 0 && x < H) ? sX[ic*HW + y*H + x] : 0.f;
        }
      }
      #pragma unroll
      for (int kh = 0; kh < 3; ++kh)
        #pragma unroll
        for (int kw = 0; kw < 3; ++kw) {
          float wv = w[kh*3+kw];
          #pragma unroll
          for (int px = 0; px < 4; ++px)
            acc[px] = fmaf(wv, rin[kh][px+kw], acc[px]);
        }
    }
  }

  // stats: same per-(oc,q) float partials as before; per-oc S/Q are the same
  // 4 floats summed in the same q-order -> identical doubles into atomics.
  {
    float ls = 0.f, lq = 0.f;
    #pragma unroll
    for (int i = 0; i < NACC; ++i) { ls += acc[i]; lq += acc[i]*acc[i]; }
    sS[tid] = ls; sQ[tid] = lq;
    __syncthreads();
    if (tid < 32) {
      float S = sS[tid] + sS[tid+32] + sS[tid+64] + sS[tid+96];
      float Q = sQ[tid] + sQ[tid+32] + sQ[tid+64] + sQ[tid+96];
      const int ocGl = tid + 32*half;
      atomicAdd(&stats[(g*64 + ocGl)*2 + 0], (double)S);
      atomicAdd(&stats[(g*64 + ocGl)*2 + 1], (double)Q);
    }
  }
  // raw pooled-max store
  if (H == 8) {
    const int py0 = ry/2, px0 = rx/2;
    #pragma unroll
    for (int pj = 0; pj < 2; ++pj)
      #pragma unroll
      for (int pi = 0; pi < 2; ++pi) {
        float mx = fmaxf(
            fmaxf(acc[(2*pj  )*4 + 2*pi], acc[(2*pj  )*4 + 2*pi+1]),
            fmaxf(acc[(2*pj+1)*4 + 2*pi], acc[(2*pj+1)*4 + 2*pi+1]));
        out[(((size_t)n*64 + oc)*4 + (py0+pj))*4 + (px0+pi)] = mx;
      }
  } else {
    __syncthreads();
    #pragma unroll
    for (int px = 0; px < 4; ++px)
      sC[ocL*16 + q*4 + px] = acc[px];
    __syncthreads();
    int oc2 = tid & 31, pj = (tid >> 5) & 1, pi = (tid >> 6) & 1;
    float m = fmaxf(
        fmaxf(sC[oc2*16 + (2*pj  )*4 + 2*pi], sC[oc2*16 + (2*pj  )*4 + 2*pi+1]),
        fmaxf(sC[oc2*16 + (2*pj+1)*4 + 2*pi], sC[oc2*16 + (2*pj+1)*4 + 2*pi+1]));
    out[(((size_t)n*64 + (oc2 + 32*half))*2 + pj)*2 + pi] = m;
  }
}

// ---------------------------------------------------------------------------
// Head: graph_means / edge_cos consume the RAW L6 pooled-max and apply L6's
// BN on load (fused bn_finalize in prologue; bit-identical arithmetic).
// feat layout [n,64,2,2] -> dim d: oc = d>>2.
// ---------------------------------------------------------------------------
__global__ void graph_means(const float* __restrict__ raw,
                            const double* __restrict__ st,
                            const float* __restrict__ gam, const float* __restrict__ bet,
                            float* __restrict__ s_cat, float* __restrict__ p_cat)
{
  int gb = blockIdx.x, d = threadIdx.x;
  const int gg = (gb < 48) ? 0 : 1;      // block's nodes are all one group
  __shared__ float sScl[64], sShf[64];
  if (d < 64) {
    double cnt  = (gg == 0) ? 192.0*4*4 : 96.0*4*4;   // L6 spatial = 4x4
    double mean = st[((size_t)gg*64 + d)*2 + 0] / cnt;
    double var  = st[((size_t)gg*64 + d)*2 + 1] / cnt - mean*mean;
    double inv  = 1.0 / sqrt(var + 1e-5);
    double ga = (double)gam[d];
    double be = (double)bet[d];
    sScl[d] = (float)(ga * inv);
    sShf[d] = (float)(be - mean * ga * inv);
  }
  __syncthreads();
  const float s = sScl[d >> 2], t = sShf[d >> 2];
  if (gb < 48) {
    float v = 0.f;
    for (int i = 0; i < 4; ++i)
      v += fmaxf(fmaf(raw[(size_t)(4*gb + i)*256 + d], s, t), 0.f);
    s_cat[gb*256 + d] = v * 0.25f;
  } else {
    int qg = gb - 48;
    float v = 0.f;
    for (int i = 0; i < 4; ++i)
      v += fmaxf(fmaf(raw[(size_t)(192 + 4*qg + i)*256 + d], s, t), 0.f);
    p_cat[qg*256 + d] = v * 0.25f;
  }
}

__global__ void edge_cos(const float* __restrict__ raw,
                         const double* __restrict__ st,
                         const float* __restrict__ gam, const float* __restrict__ bet,
                         const int* __restrict__ ei,
                         float* __restrict__ nsum, float* __restrict__ ncnt, int nEdges)
{
  int e = blockIdx.x, lane = threadIdx.x;
  __shared__ float sScl[64], sShf[64];
  {   // support edges only -> g = 0
    double cnt  = 192.0*4*4;
    double mean = st[(size_t)lane*2 + 0] / cnt;
    double var  = st[(size_t)lane*2 + 1] / cnt - mean*mean;
    double inv  = 1.0 / sqrt(var + 1e-5);
    double ga = (double)gam[lane];
    double be = (double)bet[lane];
    sScl[lane] = (float)(ga * inv);
    sShf[lane] = (float)(be - mean * ga * inv);
  }
  __syncthreads();
  int src = ei[e], dst = ei[nEdges + e];
  float dot = 0.f, nj = 0.f, ni = 0.f;
  for (int j = lane; j < 256; j += 64) {
    float s = sScl[j >> 2], t = sShf[j >> 2];
    float a = fmaxf(fmaf(raw[(size_t)src*256 + j], s, t), 0.f);
    float b = fmaxf(fmaf(raw[(size_t)dst*256 + j], s, t), 0.f);
    dot += a*b; nj += a*a; ni += b*b;
  }
  for (int off = 32; off > 0; off >>= 1) {
    dot += __shfl_down(dot, off);
    nj  += __shfl_down(nj,  off);
    ni  += __shfl_down(ni,  off);
  }
  if (lane == 0) {
    float denom = fmaxf(sqrtf(nj)*sqrtf(ni), 1e-6f);
    atomicAdd(&nsum[dst], dot/denom);
    atomicAdd(&ncnt[dst], 1.f);
  }
}

__global__ void cos_loss_k(const float* __restrict__ nsum, const float* __restrict__ ncnt,
                           float* __restrict__ cosloss)
{
  int g = threadIdx.x;
  float v = 0.f;
  if (g < 48) {
    float gm = 0.f;
    for (int i = 0; i < 4; ++i) {
      int nd = 4*g + i;
      gm += nsum[nd] / fmaxf(ncnt[nd], 1.f);
    }
    gm *= 0.25f;
    v = (gm - 1.f)*(gm - 1.f);
  }
  for (int off = 32; off > 0; off >>= 1) v += __shfl_down(v, off);
  if (g == 0) cosloss[0] = v;
}

__global__ void pd_out(const float* __restrict__ s_cat, const float* __restrict__ p_cat,
                       const int* __restrict__ support_y, const int* __restrict__ query_y,
                       float* __restrict__ ce, float* __restrict__ correct)
{
  const int q = blockIdx.x;
  const int tid = threadIdx.x, lane = tid & 63, wid = tid >> 6;
  __shared__ float sP[48];
  __shared__ float sOut[24];
  float pv[4];
  #pragma unroll
  for (int j = 0; j < 4; ++j) pv[j] = p_cat[(size_t)q*256 + lane + 64*j];
  for (int s = wid*12; s < wid*12 + 12; ++s) {
    float d2 = 0.f;
    #pragma unroll
    for (int j = 0; j < 4; ++j) {
      float diff = pv[j] - s_cat[(size_t)s*256 + lane + 64*j];
      d2 += diff*diff;
    }
    for (int off = 32; off > 0; off >>= 1) d2 += __shfl_down(d2, off);
    if (lane == 0) sP[s] = expf(-d2);
  }
  __syncthreads();
  if (tid < 24) {
    int c = tid; float sum = 0.f; int cnt = 0;
    for (int s = 0; s < 48; ++s)
      if (support_y[s] == c) { sum += sP[s]; ++cnt; }
    sOut[c] = sum / fmaxf((float)cnt, 1.f);
  }
  __syncthreads();
  if (tid == 0) {
    float m = sOut[0]; int am = 0;
    for (int c = 1; c < 24; ++c) if (sOut[c] > m) { m = sOut[c]; am = c; }
    float lse = 0.f;
    for (int c = 0; c < 24; ++c) lse += expf(sOut[c] - m);
    lse = m + logf(lse);
    int y = query_y[q];
    ce[q] = lse - sOut[y];
    correct[q] = (am == y) ? 1.f : 0.f;
  }
}

__global__ void final_k(const float* __restrict__ ce, const float* __restrict__ correct,
                        const float* __restrict__ cosloss, float* __restrict__ out)
{
  if (threadIdx.x == 0) {
    float s = 0.f, a = 0.f;
    for (int qq = 0; qq < 24; ++qq) { s += ce[qq]; a += correct[qq]; }
    float atten = ce[5];
    float rest  = (s - atten) / 23.f;
    float cl = cosloss[0];
    out[0] = atten + rest + cl;
    out[1] = a;
    out[2] = cl;
    out[3] = atten;
    out[4] = rest;
  }
}

// ---------------------------------------------------------------------------
extern "C" void kernel_launch(void* const* d_in, const int* in_sizes, int n_in,
                              void* d_out, int out_size, void* d_ws, size_t ws_size,
                              hipStream_t stream)
{
  const float* support_x = (const float*)d_in[0];
  const float* query_x   = (const float*)d_in[1];
  const int*   s_ei      = (const int*)d_in[2];
  const int*   s_y       = (const int*)d_in[6];
  const int*   q_y       = (const int*)d_in[7];
  const float* w1 = (const float*)d_in[8];
  const float* g1 = (const float*)d_in[9];
  const float* b1 = (const float*)d_in[10];
  const float* w2 = (const float*)d_in[11];
  const float* g2 = (const float*)d_in[12];
  const float* b2 = (const float*)d_in[13];
  const float* wr = (const float*)d_in[14];
  const float* gr = (const float*)d_in[15];
  const float* br = (const float*)d_in[16];
  (void)in_sizes; (void)n_in; (void)out_size;

  char* ws = (char*)d_ws;
  size_t off = 0;
  auto alloc = [&](size_t bytes) -> char* {
    char* p = ws + off;
    off = (off + bytes + 255) & ~(size_t)255;
    return p;
  };
  float*  actA  = (float*)alloc((size_t)288*32*64*64*4);   // 151 MB (L1 max-plane)
  float*  actB  = (float*)alloc((size_t)288*64*32*32*4);   // 75.5 MB (L2 max-plane)
  double* stats = (double*)alloc(6*256*8);                 // 12288 B (6 layer slots)
  float*  nsum  = (float*)alloc(192*4);                    // 768 B (contiguous w/ stats)
  float*  ncnt  = (float*)alloc(192*4);                    // 768 B
  float*  s_cat = (float*)alloc(48*256*4);
  float*  p_cat = (float*)alloc(24*256*4);
  float*  cosl  = (float*)alloc(256);
  float*  ce    = (float*)alloc(24*4);
  float*  corr  = (float*)alloc(24*4);
  if (off > ws_size) return;   // ~227 MB, known to fit

  const int NS = 192;
  const int BIG = 1 << 30;

  // L3-L6 planes reuse actA space (dead after L2 stats consumed it)
  float* mx3   = actA;                                    // 18.9 MB
  float* mx4   = actA + (size_t)288*64*16*16;             // 4.7 MB
  float* rawm5 = mx4  + (size_t)288*64*8*8;               // 1.2 MB (L5 raw pooled-max)
  float* rawm6 = rawm5 + (size_t)288*64*4*4;              // 0.3 MB (L6 raw pooled-max)

  // single memset covers stats (12288B, 256-mult) + nsum (768) + ncnt (768)
  hipMemsetAsync(stats, 0, 6*256*8 + 192*4 + 192*4, stream);

  // ---- L1: 3->32 @128, raw input. grid 288*16*2 = 9216
  conv_stats<3,32,128,32,16,false><<<9216,256,0,stream>>>(
      support_x, query_x, 192, w1, nullptr, nullptr, nullptr, 0.0, 0.0,
      stats, actA, NS);

  // ---- L2: 32->64 @64, PREBN(L1 via fused finalize). grid 4608
  conv_stats<32,64,64,32,16,true><<<4608,256,0,stream>>>(
      actA, actA, BIG, w2, stats, g1, b1, 192.0*128*128, 96.0*128*128,
      stats+256, actB, NS);

  // ---- L3: 64->64 @32, PREBN(L2). grid 1152
  conv_stats<64,64,32,32,16,true><<<1152,256,0,stream>>>(
      actB, actB, BIG, wr + 0*36864, stats+256, g2, b2, 192.0*64*64, 96.0*64*64,
      stats+512, mx3, NS);

  // ---- L4: 64->64 @16, PREBN(L3). OCG=4 (R26 criterion: reverted). grid 4608
  conv_stats<64,64,16,16,4,true><<<4608,64,0,stream>>>(
      mx3, mx3, BIG, wr + 1*36864, stats+512, gr + 0*64, br + 0*64,
      192.0*32*32, 96.0*32*32, stats+768, mx4, NS);

  // ---- L5: 64->64 @8, PREBN(L4) -> stats + raw pooled-max. 2-way oc-split.
  conv_small<8><<<576,128,0,stream>>>(
      mx4, wr + 2*36864, stats+768, gr + 1*64, br + 1*64,
      192.0*16*16, 96.0*16*16, stats+1024, rawm5, NS);

  // ---- L6: 64->64 @4, PREBN(L5) consuming rawm5 directly. 2-way oc-split.
  conv_small<4><<<576,128,0,stream>>>(
      rawm5, wr + 3*36864, stats+1024, gr + 2*64, br + 2*64,
      192.0*8*8, 96.0*8*8, stats+1280, rawm6, NS);

  // ---- head: L6 BN applied on load from rawm6
  graph_means<<<72,256,0,stream>>>(rawm6, stats+1280, gr + 3*64, br + 3*64,
                                   s_cat, p_cat);
  edge_cos<<<768,64,0,stream>>>(rawm6, stats+1280, gr + 3*64, br + 3*64,
                                s_ei, nsum, ncnt, 768);
  cos_loss_k<<<1,64,0,stream>>>(nsum, ncnt, cosl);
  pd_out<<<24,256,0,stream>>>(s_cat, p_cat, s_y, q_y, ce, corr);
  final_k<<<1,64,0,stream>>>(ce, corr, cosl, (float*)d_out);
}